// Round 1
// baseline (274.662 us; speedup 1.0000x reference)
//
#include <hip/hip_runtime.h>
#include <cstdint>
#include <cstddef>

// Problem constants
#define BB 8
#define NN 2048
#define FF 128
#define HH 128
#define SS 2

typedef _Float16 f16x8 __attribute__((ext_vector_type(8)));
typedef float f32x4 __attribute__((ext_vector_type(4)));

// ---------------------------------------------------------------------------
// Kernel A: h[b,s,n,c] = X[b,n,:]@W_w[s,c,:] + W_b[s,c]  (fp32 vector)
// Writes h transposed as fp16: h_t[((s*B+b)*128 + ch)*N + n]
// Also writes srow[(s*B+b)*N + n] = h.a_i + a_b, scol[...] = h.a_j
// ---------------------------------------------------------------------------
__global__ __launch_bounds__(256) void prep_kernel(
    const float* __restrict__ X, const float* __restrict__ Ww,
    const float* __restrict__ Wb, const float* __restrict__ ai,
    const float* __restrict__ aj, const float* __restrict__ ab,
    _Float16* __restrict__ h_t, float* __restrict__ srow, float* __restrict__ scol)
{
    const int s = blockIdx.y;
    const int b = blockIdx.x >> 7;          // 128 tiles of 16 rows per b
    const int n0 = (blockIdx.x & 127) << 4;
    const int tid = threadIdx.x;

    __shared__ float Xs[16][129];           // padded (bank spread)
    __shared__ float wTs[64][132];          // [f][c], 132*4=528B row = 16B aligned
    __shared__ float hT[128][17];           // transpose staging for coalesced store

    {   // stage X tile 16x128
        int r = tid >> 4, f0 = (tid & 15) << 3;
        const float* src = X + ((size_t)b * NN + n0 + r) * FF + f0;
        *(float4*)&Xs[r][f0]     = *(const float4*)src;
        *(float4*)&Xs[r][f0 + 4] = *(const float4*)(src + 4);
    }

    float acc[8] = {0, 0, 0, 0, 0, 0, 0, 0};
    const int tr = tid >> 4, tc = tid & 15;   // 16 rows x (16 groups x 8 ch)

    for (int fc = 0; fc < 2; ++fc) {
        __syncthreads();
        {   // stage W chunk transposed: wTs[f][c] = Ww[s][c][fc*64+f]
            int c = tid >> 1, fh = tid & 1;
            const float* wsrc = Ww + ((size_t)s * HH + c) * FF + fc * 64 + fh * 32;
            #pragma unroll
            for (int i = 0; i < 32; i += 4) {
                float4 v = *(const float4*)(wsrc + i);
                wTs[fh * 32 + i + 0][c] = v.x;
                wTs[fh * 32 + i + 1][c] = v.y;
                wTs[fh * 32 + i + 2][c] = v.z;
                wTs[fh * 32 + i + 3][c] = v.w;
            }
        }
        __syncthreads();
        #pragma unroll 8
        for (int f = 0; f < 64; ++f) {
            float x = Xs[tr][fc * 64 + f];
            float4 w0 = *(const float4*)&wTs[f][tc * 8];
            float4 w1 = *(const float4*)&wTs[f][tc * 8 + 4];
            acc[0] = fmaf(x, w0.x, acc[0]);
            acc[1] = fmaf(x, w0.y, acc[1]);
            acc[2] = fmaf(x, w0.z, acc[2]);
            acc[3] = fmaf(x, w0.w, acc[3]);
            acc[4] = fmaf(x, w1.x, acc[4]);
            acc[5] = fmaf(x, w1.y, acc[5]);
            acc[6] = fmaf(x, w1.z, acc[6]);
            acc[7] = fmaf(x, w1.w, acc[7]);
        }
    }
    {   // + W_b
        float4 b0 = *(const float4*)(Wb + s * HH + tc * 8);
        float4 b1 = *(const float4*)(Wb + s * HH + tc * 8 + 4);
        acc[0] += b0.x; acc[1] += b0.y; acc[2] += b0.z; acc[3] += b0.w;
        acc[4] += b1.x; acc[5] += b1.y; acc[6] += b1.z; acc[7] += b1.w;
    }
    {   // si/sj partials + 16-lane reduce (lanes tr*16..tr*16+15 share a row)
        float4 a0 = *(const float4*)(ai + s * HH + tc * 8);
        float4 a1 = *(const float4*)(ai + s * HH + tc * 8 + 4);
        float4 j0 = *(const float4*)(aj + s * HH + tc * 8);
        float4 j1 = *(const float4*)(aj + s * HH + tc * 8 + 4);
        float pi = acc[0]*a0.x + acc[1]*a0.y + acc[2]*a0.z + acc[3]*a0.w
                 + acc[4]*a1.x + acc[5]*a1.y + acc[6]*a1.z + acc[7]*a1.w;
        float pj = acc[0]*j0.x + acc[1]*j0.y + acc[2]*j0.z + acc[3]*j0.w
                 + acc[4]*j1.x + acc[5]*j1.y + acc[6]*j1.z + acc[7]*j1.w;
        #pragma unroll
        for (int m = 1; m < 16; m <<= 1) {
            pi += __shfl_xor(pi, m);
            pj += __shfl_xor(pj, m);
        }
        if (tc == 0) {
            size_t idx = (size_t)(s * BB + b) * NN + n0 + tr;
            srow[idx] = pi + ab[s];   // fold attn bias into row term
            scol[idx] = pj;
        }
    }
    #pragma unroll
    for (int i = 0; i < 8; ++i) hT[tc * 8 + i][tr] = acc[i];
    __syncthreads();
    {   // coalesced fp16 store of transposed h
        int ch = tid >> 1, nh = (tid & 1) * 8;
        f16x8 v;
        #pragma unroll
        for (int i = 0; i < 8; ++i) v[i] = (_Float16)hT[ch][nh + i];
        *(f16x8*)(h_t + ((size_t)((s * BB + b) * HH + ch)) * NN + n0 + nh) = v;
    }
}

// ---------------------------------------------------------------------------
// Kernel B: fused e-compute + online softmax + P@h via fp16 MFMA.
// Block: 256 thr = 4 waves, TM=64 rows, TK=64 per j-tile.
// Wave w: kt = w&1 (K-half of tile), chh = w>>1 (ch half). Wave tile 64x64,
// 4x4 fragments (16x16x32), acc split-K summed in LDS at epilogue.
// LDS: P [64][64] f16 swizzled @0 (8KB), hT [128][64] f16 swizzled @8192
// (16KB), epilogue f32 [64][128] @0 (32KB), stats @32768.
// ---------------------------------------------------------------------------
__global__ __launch_bounds__(256) void attn_kernel(
    const float* __restrict__ dist, const float* __restrict__ sigmas,
    const float* __restrict__ thr, const _Float16* __restrict__ h_t,
    const float* __restrict__ srow, const float* __restrict__ scol,
    float* __restrict__ Hcat)
{
    const int s = blockIdx.z, b = blockIdx.y;
    const int i0 = blockIdx.x * 64;
    const int tid = threadIdx.x;

    __shared__ __align__(16) unsigned char smem[33536];
    float* m_row  = (float*)(smem + 32768);        // [64]
    float* l_row  = (float*)(smem + 32768 + 256);  // [64]
    float* sc_row = (float*)(smem + 32768 + 512);  // [64]

    const float sg = sigmas[s];
    const float inv2s2 = 1.0f / (2.0f * sg * sg);
    const float th = thr[s];
    const size_t sb = (size_t)(s * BB + b) * NN;
    const _Float16* hbase = h_t + (size_t)(s * BB + b) * HH * NN;

    if (tid < 64) { m_row[tid] = -INFINITY; l_row[tid] = 0.0f; }

    f32x4 acc[4][4];
    #pragma unroll
    for (int m = 0; m < 4; ++m)
        #pragma unroll
        for (int n = 0; n < 4; ++n) acc[m][n] = (f32x4){0.f, 0.f, 0.f, 0.f};

    const int wave = tid >> 6, lane = tid & 63;
    const int kt = wave & 1, chh = wave >> 1;
    const int lm = lane & 15;
    const int rbase = (lane >> 4) * 4;                  // C/D rows per lane
    const unsigned kbyte = (kt * 32 + (lane >> 4) * 8) * 2;

    // phase-1 geometry: 64 rows x 4 j-groups of 16
    const int row = tid >> 2, jj = tid & 3;
    const int gi = i0 + row;
    const float si = srow[sb + gi];

    __syncthreads();

    for (int jt = 0; jt < 32; ++jt) {
        const int j0 = jt * 64;
        // ---------------- phase 1: e -> online softmax -> P (fp16, swizzled)
        const int jbase = j0 + jj * 16;
        const float* dp = dist + (size_t)gi * NN + jbase;
        const float* sp = scol + sb + jbase;
        float dv[16], cv[16];
        *(float4*)&dv[0]  = *(const float4*)(dp + 0);
        *(float4*)&dv[4]  = *(const float4*)(dp + 4);
        *(float4*)&dv[8]  = *(const float4*)(dp + 8);
        *(float4*)&dv[12] = *(const float4*)(dp + 12);
        *(float4*)&cv[0]  = *(const float4*)(sp + 0);
        *(float4*)&cv[4]  = *(const float4*)(sp + 4);
        *(float4*)&cv[8]  = *(const float4*)(sp + 8);
        *(float4*)&cv[12] = *(const float4*)(sp + 12);

        float e[16];
        #pragma unroll
        for (int k = 0; k < 16; ++k) {
            float d = dv[k];
            float A = __expf(-d * d * inv2s2);
            float msk = __builtin_amdgcn_rcpf(1.0f + __expf(-10.0f * (A - th)));
            float dd = (gi == jbase + k) ? 1.0f : d;      // diag=1 for 1/d term only
            float invd = __builtin_amdgcn_rcpf(dd + 1e-5f);
            float e0 = si + cv[k];
            e0 = (e0 >= 0.0f) ? e0 : 0.1f * e0;           // LeakyReLU
            e[k] = (e0 + invd) * msk;
        }
        float mt = e[0];
        #pragma unroll
        for (int k = 1; k < 16; ++k) mt = fmaxf(mt, e[k]);
        mt = fmaxf(mt, __shfl_xor(mt, 1));
        mt = fmaxf(mt, __shfl_xor(mt, 2));
        float m_old = m_row[row];
        float m_new = fmaxf(m_old, mt);
        float psum = 0.0f;
        f16x8 p0, p1;
        #pragma unroll
        for (int k = 0; k < 8; ++k) {
            float p = __expf(e[k] - m_new);
            psum += p; p0[k] = (_Float16)p;
        }
        #pragma unroll
        for (int k = 8; k < 16; ++k) {
            float p = __expf(e[k] - m_new);
            psum += p; p1[k - 8] = (_Float16)p;
        }
        psum += __shfl_xor(psum, 1);
        psum += __shfl_xor(psum, 2);
        {
            unsigned base = row * 128, sw = (row & 7) << 4;
            *(f16x8*)(smem + base + ((jj * 32)      ^ sw)) = p0;
            *(f16x8*)(smem + base + ((jj * 32 + 16) ^ sw)) = p1;
        }
        if (jj == 0) {
            float scl = __expf(m_old - m_new);   // 0 on first tile (m_old=-inf)
            m_row[row] = m_new;
            sc_row[row] = scl;
            l_row[row] = l_row[row] * scl + psum;
        }
        // ---------------- stage h tile [128 ch][64 k] fp16, swizzled
        #pragma unroll
        for (int it = 0; it < 4; ++it) {
            int idx = tid + it * 256;
            int ch = idx >> 3, seg = idx & 7;
            f16x8 v = *(const f16x8*)(hbase + (size_t)ch * NN + j0 + seg * 8);
            *(f16x8*)(smem + 8192 + ch * 128 + ((seg * 16) ^ ((ch & 7) << 4))) = v;
        }
        __syncthreads();
        // ---------------- phase 2: rescale + MFMA
        f16x8 af[4], bf[4];
        #pragma unroll
        for (int m = 0; m < 4; ++m) {
            int r = m * 16 + lm;
            af[m] = *(const f16x8*)(smem + r * 128 + (kbyte ^ ((r & 7) << 4)));
        }
        #pragma unroll
        for (int n = 0; n < 4; ++n) {
            int ch = chh * 64 + n * 16 + lm;
            bf[n] = *(const f16x8*)(smem + 8192 + ch * 128 + (kbyte ^ ((ch & 7) << 4)));
        }
        #pragma unroll
        for (int m = 0; m < 4; ++m) {
            f32x4 scv = *(const f32x4*)&sc_row[m * 16 + rbase];
            #pragma unroll
            for (int n = 0; n < 4; ++n) {
                acc[m][n] *= scv;
                acc[m][n] = __builtin_amdgcn_mfma_f32_16x16x32_f16(af[m], bf[n], acc[m][n], 0, 0, 0);
            }
        }
        __syncthreads();
    }

    // ---------------- epilogue: split-K sum in LDS, divide by l, store
    float* ebuf = (float*)smem;   // [64][128]
    if (kt == 0) {
        #pragma unroll
        for (int m = 0; m < 4; ++m)
            #pragma unroll
            for (int n = 0; n < 4; ++n)
                #pragma unroll
                for (int r = 0; r < 4; ++r)
                    ebuf[(m * 16 + rbase + r) * 128 + chh * 64 + n * 16 + lm] = acc[m][n][r];
    }
    __syncthreads();
    if (kt == 1) {
        #pragma unroll
        for (int m = 0; m < 4; ++m)
            #pragma unroll
            for (int n = 0; n < 4; ++n)
                #pragma unroll
                for (int r = 0; r < 4; ++r)
                    ebuf[(m * 16 + rbase + r) * 128 + chh * 64 + n * 16 + lm] += acc[m][n][r];
    }
    __syncthreads();
    {
        #pragma unroll
        for (int rr = 0; rr < 8; ++rr) {
            int r2 = rr * 8 + (tid >> 5);
            int c4 = (tid & 31) * 4;
            float inv = 1.0f / l_row[r2];
            float4 v = *(float4*)&ebuf[r2 * 128 + c4];
            v.x *= inv; v.y *= inv; v.z *= inv; v.w *= inv;
            *(float4*)(Hcat + ((size_t)(b * NN + i0 + r2)) * (SS * HH) + s * HH + c4) = v;
        }
    }
}

// ---------------------------------------------------------------------------
// Kernel C: out[b,n,h] = Hcat[b,n,:] @ fus_w[h,:] + fus_b[h]  (fp32 vector)
// ---------------------------------------------------------------------------
__global__ __launch_bounds__(256) void fuse_kernel(
    const float* __restrict__ Hcat, const float* __restrict__ fw,
    const float* __restrict__ fb, float* __restrict__ out)
{
    const int b = blockIdx.x >> 7;
    const int n0 = (blockIdx.x & 127) << 4;
    const int tid = threadIdx.x;

    __shared__ float Hs[16][260];   // 260*4=1040B row, 16B aligned
    __shared__ float wTs[64][132];

    {   // stage Hcat tile 16 x 256
        int r = tid >> 4, k0 = (tid & 15) * 16;
        const float* src = Hcat + ((size_t)(b * NN + n0 + r)) * (SS * HH) + k0;
        #pragma unroll
        for (int i = 0; i < 16; i += 4)
            *(float4*)&Hs[r][k0 + i] = *(const float4*)(src + i);
    }
    float acc[8] = {0, 0, 0, 0, 0, 0, 0, 0};
    const int tr = tid >> 4, tc = tid & 15;

    for (int kc = 0; kc < 4; ++kc) {
        __syncthreads();
        {   // stage fus_w chunk transposed: wTs[kk][h] = fw[h][kc*64+kk]
            int c = tid >> 1, kh = tid & 1;
            const float* wsrc = fw + (size_t)c * (SS * HH) + kc * 64 + kh * 32;
            #pragma unroll
            for (int i = 0; i < 32; i += 4) {
                float4 v = *(const float4*)(wsrc + i);
                wTs[kh * 32 + i + 0][c] = v.x;
                wTs[kh * 32 + i + 1][c] = v.y;
                wTs[kh * 32 + i + 2][c] = v.z;
                wTs[kh * 32 + i + 3][c] = v.w;
            }
        }
        __syncthreads();
        #pragma unroll 8
        for (int k = 0; k < 64; ++k) {
            float x = Hs[tr][kc * 64 + k];
            float4 w0 = *(const float4*)&wTs[k][tc * 8];
            float4 w1 = *(const float4*)&wTs[k][tc * 8 + 4];
            acc[0] = fmaf(x, w0.x, acc[0]);
            acc[1] = fmaf(x, w0.y, acc[1]);
            acc[2] = fmaf(x, w0.z, acc[2]);
            acc[3] = fmaf(x, w0.w, acc[3]);
            acc[4] = fmaf(x, w1.x, acc[4]);
            acc[5] = fmaf(x, w1.y, acc[5]);
            acc[6] = fmaf(x, w1.z, acc[6]);
            acc[7] = fmaf(x, w1.w, acc[7]);
        }
    }
    {
        float4 b0 = *(const float4*)(fb + tc * 8);
        float4 b1 = *(const float4*)(fb + tc * 8 + 4);
        acc[0] += b0.x; acc[1] += b0.y; acc[2] += b0.z; acc[3] += b0.w;
        acc[4] += b1.x; acc[5] += b1.y; acc[6] += b1.z; acc[7] += b1.w;
        float* dst = out + ((size_t)(b * NN + n0 + tr)) * HH + tc * 8;
        *(float4*)dst       = (float4){acc[0], acc[1], acc[2], acc[3]};
        *(float4*)(dst + 4) = (float4){acc[4], acc[5], acc[6], acc[7]};
    }
}

// ---------------------------------------------------------------------------
extern "C" void kernel_launch(void* const* d_in, const int* in_sizes, int n_in,
                              void* d_out, int out_size, void* d_ws, size_t ws_size,
                              hipStream_t stream)
{
    const float* X      = (const float*)d_in[0];
    const float* dist   = (const float*)d_in[1];
    const float* sigmas = (const float*)d_in[2];
    const float* Ww     = (const float*)d_in[3];
    const float* Wb     = (const float*)d_in[4];
    const float* ai     = (const float*)d_in[5];
    const float* aj     = (const float*)d_in[6];
    const float* ab     = (const float*)d_in[7];
    const float* thr    = (const float*)d_in[8];
    const float* fw     = (const float*)d_in[9];
    const float* fb     = (const float*)d_in[10];
    float* out = (float*)d_out;

    // workspace layout (needs ~25.4 MB)
    char* ws = (char*)d_ws;
    _Float16* h_t = (_Float16*)ws;                               // 2*8*128*2048*2 = 8,388,608 B
    float* srow   = (float*)(ws + 8388608);                      // 131,072 B
    float* scol   = (float*)(ws + 8388608 + 131072);             // 131,072 B
    float* Hcat   = (float*)(ws + 8388608 + 262144);             // 16,777,216 B

    prep_kernel<<<dim3(BB * NN / 16, SS), 256, 0, stream>>>(X, Ww, Wb, ai, aj, ab, h_t, srow, scol);
    attn_kernel<<<dim3(NN / 64, BB, SS), 256, 0, stream>>>(dist, sigmas, thr, h_t, srow, scol, Hcat);
    fuse_kernel<<<dim3(BB * NN / 16), 256, 0, stream>>>(Hcat, fw, fb, out);
}

// Round 2
// 192.614 us; speedup vs baseline: 1.4260x; 1.4260x over previous
//
#include <hip/hip_runtime.h>
#include <cstdint>
#include <cstddef>

#define BB 8
#define NN 2048
#define FF 128
#define HH 128
#define SS 2

typedef _Float16 f16x8 __attribute__((ext_vector_type(8)));
typedef _Float16 f16x4 __attribute__((ext_vector_type(4)));
typedef float f32x4 __attribute__((ext_vector_type(4)));

// ---------------------------------------------------------------------------
// K0: w_ai[s][f] = sum_ch Ww[s][ch][f]*ai[s][ch]; same for aj.
// cst[0..1] = Wb[s]·ai[s] + ab[s]; cst[2..3] = Wb[s]·aj[s].
// ---------------------------------------------------------------------------
__global__ void k0_proj(const float* __restrict__ Ww, const float* __restrict__ Wb,
                        const float* __restrict__ ai, const float* __restrict__ aj,
                        const float* __restrict__ ab,
                        float* __restrict__ w_ai, float* __restrict__ w_aj,
                        float* __restrict__ cst)
{
    const int t = threadIdx.x;
    const int s = t >> 7, f = t & 127;
    const float* wp = Ww + (size_t)s * HH * FF + f;
    const float* aip = ai + s * HH;
    const float* ajp = aj + s * HH;
    float accI = 0.f, accJ = 0.f;
    for (int c = 0; c < HH; ++c) {
        float w = wp[(size_t)c * FF];
        accI = fmaf(w, aip[c], accI);
        accJ = fmaf(w, ajp[c], accJ);
    }
    w_ai[s * FF + f] = accI;
    w_aj[s * FF + f] = accJ;
    if (t < 2 * SS) {
        int ss = t & 1; bool isI = t < 2;
        const float* av = (isI ? ai : aj) + ss * HH;
        const float* wb = Wb + ss * HH;
        float c = 0.f;
        for (int k = 0; k < HH; ++k) c = fmaf(wb[k], av[k], c);
        if (isI) c += ab[ss];
        cst[t] = c;
    }
}

// ---------------------------------------------------------------------------
// geo: g1[s][i][j] = mask (f16), g2[s][i][j] = mask*inv_d (f32, exact div)
// ---------------------------------------------------------------------------
__global__ __launch_bounds__(256) void geo_kernel(
    const float* __restrict__ dist, const float* __restrict__ sigmas,
    const float* __restrict__ thr, _Float16* __restrict__ g1, float* __restrict__ g2)
{
    const size_t idx = ((size_t)blockIdx.x * 256 + threadIdx.x) * 8;
    const int s = (int)(idx >> 22);
    const int i = (int)((idx >> 11) & (NN - 1));
    const int j0 = (int)(idx & (NN - 1));
    const float sg = sigmas[s];
    const float inv2s2 = 1.0f / (2.0f * sg * sg);
    const float th = thr[s];
    const float* dp = dist + (size_t)i * NN + j0;
    float4 d0 = *(const float4*)dp, d1 = *(const float4*)(dp + 4);
    float dv[8] = {d0.x, d0.y, d0.z, d0.w, d1.x, d1.y, d1.z, d1.w};
    f16x8 o1; float og[8];
    #pragma unroll
    for (int k = 0; k < 8; ++k) {
        float d = dv[k];
        float A = __expf(-d * d * inv2s2);
        float msk = 1.0f / (1.0f + __expf(-10.0f * (A - th)));
        float dd = (j0 + k == i) ? 1.0f : d;
        float invd = 1.0f / (dd + 1e-5f);
        o1[k] = (_Float16)msk;
        og[k] = msk * invd;
    }
    *(f16x8*)(g1 + idx) = o1;
    *(float4*)(g2 + idx)     = (float4){og[0], og[1], og[2], og[3]};
    *(float4*)(g2 + idx + 4) = (float4){og[4], og[5], og[6], og[7]};
}

// ---------------------------------------------------------------------------
// prep: h = X@W^T (+Wb) via fp16 MFMA; writes h_t[sb][ch][n] f16 and
// srow/scol from LDS X-tile dotted with w_ai/w_aj.
// LDS: Xs [64 rows][256B] (128 f16, 16 slots, XOR r&15), Wt [128][256B] @16384.
// ---------------------------------------------------------------------------
__global__ __launch_bounds__(256, 2) void prep_kernel(
    const float* __restrict__ X, const float* __restrict__ Ww, const float* __restrict__ Wb,
    const float* __restrict__ w_ai, const float* __restrict__ w_aj, const float* __restrict__ cst,
    _Float16* __restrict__ h_t, float* __restrict__ srow, float* __restrict__ scol)
{
    const int s = blockIdx.z, b = blockIdx.y;
    const int n0 = blockIdx.x * 64;
    const int tid = threadIdx.x;
    __shared__ __align__(16) unsigned char smem[49152];

    {   // stage Xs (fp32 -> f16, swizzled)
        const int r = tid >> 2, fq = tid & 3;
        const float* src = X + ((size_t)b * NN + n0 + r) * FF + fq * 32;
        unsigned char* dst = smem + r * 256;
        const unsigned rs = r & 15;
        #pragma unroll
        for (int k = 0; k < 4; ++k) {
            float4 v0 = *(const float4*)(src + k * 8);
            float4 v1 = *(const float4*)(src + k * 8 + 4);
            f16x8 h;
            h[0] = (_Float16)v0.x; h[1] = (_Float16)v0.y; h[2] = (_Float16)v0.z; h[3] = (_Float16)v0.w;
            h[4] = (_Float16)v1.x; h[5] = (_Float16)v1.y; h[6] = (_Float16)v1.z; h[7] = (_Float16)v1.w;
            *(f16x8*)(dst + (((fq * 4 + k) ^ rs) << 4)) = h;
        }
    }
    {   // stage Wt (fp32 -> f16, swizzled)
        const int ch = tid >> 1, kh8 = (tid & 1) * 8;
        const float* src = Ww + ((size_t)s * HH + ch) * FF + kh8 * 8;
        unsigned char* dst = smem + 16384 + ch * 256;
        const unsigned cs = ch & 15;
        #pragma unroll
        for (int k = 0; k < 8; ++k) {
            float4 v0 = *(const float4*)(src + k * 8);
            float4 v1 = *(const float4*)(src + k * 8 + 4);
            f16x8 h;
            h[0] = (_Float16)v0.x; h[1] = (_Float16)v0.y; h[2] = (_Float16)v0.z; h[3] = (_Float16)v0.w;
            h[4] = (_Float16)v1.x; h[5] = (_Float16)v1.y; h[6] = (_Float16)v1.z; h[7] = (_Float16)v1.w;
            *(f16x8*)(dst + (((kh8 + k) ^ cs) << 4)) = h;
        }
    }
    __syncthreads();

    const int wave = tid >> 6, lane = tid & 63;
    const int lm = lane & 15, lq = lane >> 4, rbase = lq * 4;
    f32x4 acc[4][2];
    #pragma unroll
    for (int m = 0; m < 4; ++m)
        #pragma unroll
        for (int n = 0; n < 2; ++n) acc[m][n] = (f32x4){0.f, 0.f, 0.f, 0.f};

    #pragma unroll
    for (int ks = 0; ks < 4; ++ks) {
        f16x8 af[4], bf[2];
        #pragma unroll
        for (int m = 0; m < 4; ++m) {
            int r = m * 16 + lm;
            af[m] = *(const f16x8*)(smem + r * 256 + ((((ks << 2) | lq) ^ (r & 15)) << 4));
        }
        #pragma unroll
        for (int n = 0; n < 2; ++n) {
            int ch = wave * 32 + n * 16 + lm;
            bf[n] = *(const f16x8*)(smem + 16384 + ch * 256 + ((((ks << 2) | lq) ^ (ch & 15)) << 4));
        }
        #pragma unroll
        for (int m = 0; m < 4; ++m)
            #pragma unroll
            for (int n = 0; n < 2; ++n)
                acc[m][n] = __builtin_amdgcn_mfma_f32_16x16x32_f16(af[m], bf[n], acc[m][n], 0, 0, 0);
    }
    {   // + Wb, store h_t transposed
        float wb0 = Wb[s * HH + wave * 32 + lm];
        float wb1 = Wb[s * HH + wave * 32 + 16 + lm];
        #pragma unroll
        for (int m = 0; m < 4; ++m)
            #pragma unroll
            for (int n = 0; n < 2; ++n) {
                float wb = n ? wb1 : wb0;
                f16x4 hv;
                #pragma unroll
                for (int r = 0; r < 4; ++r) hv[r] = (_Float16)(acc[m][n][r] + wb);
                int ch = wave * 32 + n * 16 + lm;
                *(f16x4*)(h_t + ((size_t)((s * BB + b) * HH + ch)) * NN + n0 + m * 16 + rbase) = hv;
            }
    }
    {   // si/sj from Xs LDS
        const int r = tid >> 2, q = tid & 3;
        const unsigned char* xrow = smem + r * 256;
        const unsigned rs = r & 15;
        const float* wi = w_ai + s * FF + q * 32;
        const float* wj = w_aj + s * FF + q * 32;
        float pi = 0.f, pj = 0.f;
        #pragma unroll
        for (int k = 0; k < 4; ++k) {
            f16x8 xv = *(const f16x8*)(xrow + (((q * 4 + k) ^ rs) << 4));
            float4 wi0 = *(const float4*)(wi + k * 8), wi1 = *(const float4*)(wi + k * 8 + 4);
            float4 wj0 = *(const float4*)(wj + k * 8), wj1 = *(const float4*)(wj + k * 8 + 4);
            pi += (float)xv[0]*wi0.x + (float)xv[1]*wi0.y + (float)xv[2]*wi0.z + (float)xv[3]*wi0.w
                + (float)xv[4]*wi1.x + (float)xv[5]*wi1.y + (float)xv[6]*wi1.z + (float)xv[7]*wi1.w;
            pj += (float)xv[0]*wj0.x + (float)xv[1]*wj0.y + (float)xv[2]*wj0.z + (float)xv[3]*wj0.w
                + (float)xv[4]*wj1.x + (float)xv[5]*wj1.y + (float)xv[6]*wj1.z + (float)xv[7]*wj1.w;
        }
        pi += __shfl_xor(pi, 1); pi += __shfl_xor(pi, 2);
        pj += __shfl_xor(pj, 1); pj += __shfl_xor(pj, 2);
        if (q == 0) {
            size_t idx = (size_t)(s * BB + b) * NN + n0 + r;
            srow[idx] = pi + cst[s];
            scol[idx] = pj + cst[2 + s];
        }
    }
}

// ---------------------------------------------------------------------------
// attn: TM=32 rows, TK=64. 4 waves; wave = ch-quarter (32 ch), full K.
// LDS: P [32][128B] @0 (XOR (row&7)<<4), hT [128][256B] @4096 (XOR ch&15 on
// 16B slots), stats @36864. ebuf f16 [32][128] reuses @0 after the loop.
// ---------------------------------------------------------------------------
template<bool GEO>
__global__ __launch_bounds__(256, 4) void attn_kernel(
    const float* __restrict__ dist, const float* __restrict__ sigmas,
    const float* __restrict__ thr, const _Float16* __restrict__ h_t,
    const float* __restrict__ srow, const float* __restrict__ scol,
    const _Float16* __restrict__ g1, const float* __restrict__ g2,
    _Float16* __restrict__ Hcat)
{
    const int s = blockIdx.z, b = blockIdx.y;
    const int i0 = blockIdx.x * 32;
    const int tid = threadIdx.x;

    __shared__ __align__(16) unsigned char smem[37248];
    float* m_row  = (float*)(smem + 36864);
    float* l_row  = (float*)(smem + 36864 + 128);
    float* sc_row = (float*)(smem + 36864 + 256);

    const size_t sb = (size_t)(s * BB + b) * NN;
    const _Float16* hbase = h_t + (size_t)(s * BB + b) * HH * NN;

    float inv2s2 = 0.f, th = 0.f;
    if (!GEO) {
        float sg = sigmas[s];
        inv2s2 = 1.0f / (2.0f * sg * sg);
        th = thr[s];
    }

    if (tid < 32) { m_row[tid] = -INFINITY; l_row[tid] = 0.f; }

    f32x4 acc[2][2];
    #pragma unroll
    for (int m = 0; m < 2; ++m)
        #pragma unroll
        for (int n = 0; n < 2; ++n) acc[m][n] = (f32x4){0.f, 0.f, 0.f, 0.f};

    const int wave = tid >> 6, lane = tid & 63;
    const int lm = lane & 15, lq = lane >> 4, rbase = lq * 4;
    const int chq = wave;

    const int row = tid >> 3, jg = tid & 7;
    const int gi = i0 + row;
    const float si = srow[sb + gi];
    const size_t girow = GEO ? ((size_t)s * NN + gi) * NN : (size_t)gi * NN;

    __syncthreads();

    for (int jt = 0; jt < NN / 64; ++jt) {
        const int j0 = jt * 64;
        const int jb = j0 + jg * 8;
        float e[8];
        {
            float4 c0 = *(const float4*)(scol + sb + jb);
            float4 c1 = *(const float4*)(scol + sb + jb + 4);
            float cv[8] = {c0.x, c0.y, c0.z, c0.w, c1.x, c1.y, c1.z, c1.w};
            if (GEO) {
                f16x8 gv = *(const f16x8*)(g1 + girow + jb);
                float4 q0 = *(const float4*)(g2 + girow + jb);
                float4 q1 = *(const float4*)(g2 + girow + jb + 4);
                float gg[8] = {q0.x, q0.y, q0.z, q0.w, q1.x, q1.y, q1.z, q1.w};
                #pragma unroll
                for (int k = 0; k < 8; ++k) {
                    float t = si + cv[k];
                    float lr = fmaxf(t, 0.1f * t);
                    e[k] = fmaf(lr, (float)gv[k], gg[k]);
                }
            } else {
                float4 d0 = *(const float4*)(dist + girow + jb);
                float4 d1 = *(const float4*)(dist + girow + jb + 4);
                float dv[8] = {d0.x, d0.y, d0.z, d0.w, d1.x, d1.y, d1.z, d1.w};
                #pragma unroll
                for (int k = 0; k < 8; ++k) {
                    float d = dv[k];
                    float A = __expf(-d * d * inv2s2);
                    float den = 1.0f + __expf(-10.0f * (A - th));
                    float r1 = __builtin_amdgcn_rcpf(den); r1 = r1 * (2.0f - den * r1);
                    float dd = (jb + k == gi) ? 1.0f : d;
                    float x2 = dd + 1e-5f;
                    float ri = __builtin_amdgcn_rcpf(x2); ri = ri * (2.0f - x2 * ri);
                    float t = si + cv[k];
                    float lr = fmaxf(t, 0.1f * t);
                    e[k] = (lr + ri) * r1;
                }
            }
        }
        float mt = fmaxf(fmaxf(fmaxf(e[0], e[1]), fmaxf(e[2], e[3])),
                         fmaxf(fmaxf(e[4], e[5]), fmaxf(e[6], e[7])));
        mt = fmaxf(mt, __shfl_xor(mt, 1));
        mt = fmaxf(mt, __shfl_xor(mt, 2));
        mt = fmaxf(mt, __shfl_xor(mt, 4));
        const float m_old = m_row[row];
        const float m_new = fmaxf(m_old, mt);
        float psum = 0.f;
        f16x8 pv;
        #pragma unroll
        for (int k = 0; k < 8; ++k) {
            float p = __expf(e[k] - m_new);
            psum += p;
            pv[k] = (_Float16)p;
        }
        psum += __shfl_xor(psum, 1);
        psum += __shfl_xor(psum, 2);
        psum += __shfl_xor(psum, 4);
        *(f16x8*)(smem + row * 128 + ((jg * 16) ^ ((row & 7) << 4))) = pv;
        if (jg == 0) {
            float scl = __expf(m_old - m_new);
            m_row[row] = m_new;
            sc_row[row] = scl;
            l_row[row] = l_row[row] * scl + psum;
        }
        {   // stage hT [128 ch][64 k] f16
            const int ch = tid >> 1, hf = tid & 1;
            const _Float16* hsrc = hbase + (size_t)ch * NN + j0 + hf * 32;
            unsigned char* hdst = smem + 4096 + ch * 256;
            const unsigned cs = ch & 15;
            #pragma unroll
            for (int q = 0; q < 4; ++q) {
                f16x8 v = *(const f16x8*)(hsrc + q * 8);
                *(f16x8*)(hdst + (((hf * 4 + q) ^ cs) << 4)) = v;
            }
        }
        __syncthreads();
        {   // MFMA
            f16x8 af[2][2], bf[2][2];
            #pragma unroll
            for (int m = 0; m < 2; ++m) {
                int r = m * 16 + lm;
                unsigned sw = (r & 7) << 4;
                af[m][0] = *(const f16x8*)(smem + r * 128 + ((lq * 16) ^ sw));
                af[m][1] = *(const f16x8*)(smem + r * 128 + ((64 + lq * 16) ^ sw));
            }
            #pragma unroll
            for (int n = 0; n < 2; ++n) {
                int ch = chq * 32 + n * 16 + lm;
                const unsigned cs = ch & 15;
                bf[n][0] = *(const f16x8*)(smem + 4096 + ch * 256 + ((lq ^ cs) << 4));
                bf[n][1] = *(const f16x8*)(smem + 4096 + ch * 256 + (((4 | lq) ^ cs) << 4));
            }
            #pragma unroll
            for (int m = 0; m < 2; ++m) {
                f32x4 scv = *(const f32x4*)&sc_row[m * 16 + rbase];
                #pragma unroll
                for (int n = 0; n < 2; ++n) {
                    acc[m][n] *= scv;
                    acc[m][n] = __builtin_amdgcn_mfma_f32_16x16x32_f16(af[m][0], bf[n][0], acc[m][n], 0, 0, 0);
                    acc[m][n] = __builtin_amdgcn_mfma_f32_16x16x32_f16(af[m][1], bf[n][1], acc[m][n], 0, 0, 0);
                }
            }
        }
        __syncthreads();
    }

    // epilogue: divide by l, f16 to ebuf, coalesced store
    _Float16* ebuf = (_Float16*)smem;
    #pragma unroll
    for (int m = 0; m < 2; ++m) {
        f32x4 lv = *(const f32x4*)&l_row[m * 16 + rbase];
        f32x4 inv;
        #pragma unroll
        for (int r = 0; r < 4; ++r) inv[r] = __builtin_amdgcn_rcpf(lv[r]);
        #pragma unroll
        for (int n = 0; n < 2; ++n)
            #pragma unroll
            for (int r = 0; r < 4; ++r)
                ebuf[(m * 16 + rbase + r) * 128 + chq * 32 + n * 16 + lm] =
                    (_Float16)(acc[m][n][r] * inv[r]);
    }
    __syncthreads();
    {
        const int r = tid >> 3, c0 = (tid & 7) * 16;
        f16x8 v0 = *(const f16x8*)(ebuf + r * 128 + c0);
        f16x8 v1 = *(const f16x8*)(ebuf + r * 128 + c0 + 8);
        _Float16* dst = Hcat + ((size_t)(b * NN + i0 + r)) * (SS * HH) + s * HH + c0;
        *(f16x8*)dst = v0;
        *(f16x8*)(dst + 8) = v1;
    }
}

// ---------------------------------------------------------------------------
// fuse: out = Hcat(f16) @ fus_w^T + fus_b via fp16 MFMA. 64-row tiles, K=256.
// LDS: Hc [64][512B] @0 (32 slots, XOR r&7), Wt [128][256B] @32768 (XOR ch&15).
// ---------------------------------------------------------------------------
__global__ __launch_bounds__(256, 2) void fuse_kernel(
    const _Float16* __restrict__ Hcat, const float* __restrict__ fw,
    const float* __restrict__ fb, float* __restrict__ out)
{
    const int r0 = blockIdx.x * 64;
    const int tid = threadIdx.x;
    __shared__ __align__(16) unsigned char smem[65536];

    {   // stage Hc full K=256 f16
        const int r = tid >> 2, q = tid & 3;
        const _Float16* src = Hcat + (size_t)(r0 + r) * 256 + q * 64;
        unsigned char* dst = smem + r * 512;
        const unsigned rs = r & 7;
        #pragma unroll
        for (int k = 0; k < 8; ++k) {
            f16x8 v = *(const f16x8*)(src + k * 8);
            *(f16x8*)(dst + (((q * 8 + k) ^ rs) << 4)) = v;
        }
    }

    const int wave = tid >> 6, lane = tid & 63;
    const int lm = lane & 15, lq = lane >> 4, rbase = lq * 4;
    f32x4 acc[4][2];
    #pragma unroll
    for (int m = 0; m < 4; ++m)
        #pragma unroll
        for (int n = 0; n < 2; ++n) acc[m][n] = (f32x4){0.f, 0.f, 0.f, 0.f};

    for (int c = 0; c < 2; ++c) {
        __syncthreads();   // protects Wt re-stage (and orders Hc stage on c=0 via next sync)
        {   // stage Wt chunk (fp32->f16)
            const int ch = tid >> 1, kh8 = (tid & 1) * 8;
            const float* src = fw + (size_t)ch * 256 + c * 128 + kh8 * 8;
            unsigned char* dst = smem + 32768 + ch * 256;
            const unsigned cs = ch & 15;
            #pragma unroll
            for (int k = 0; k < 8; ++k) {
                float4 v0 = *(const float4*)(src + k * 8);
                float4 v1 = *(const float4*)(src + k * 8 + 4);
                f16x8 h;
                h[0] = (_Float16)v0.x; h[1] = (_Float16)v0.y; h[2] = (_Float16)v0.z; h[3] = (_Float16)v0.w;
                h[4] = (_Float16)v1.x; h[5] = (_Float16)v1.y; h[6] = (_Float16)v1.z; h[7] = (_Float16)v1.w;
                *(f16x8*)(dst + (((kh8 + k) ^ cs) << 4)) = h;
            }
        }
        __syncthreads();
        #pragma unroll
        for (int ks = 0; ks < 4; ++ks) {
            const int gks = c * 4 + ks;
            f16x8 af[4], bf[2];
            #pragma unroll
            for (int m = 0; m < 4; ++m) {
                int r = m * 16 + lm;
                af[m] = *(const f16x8*)(smem + r * 512 + ((((gks << 2) | lq) ^ (r & 7)) << 4));
            }
            #pragma unroll
            for (int n = 0; n < 2; ++n) {
                int ch = wave * 32 + n * 16 + lm;
                bf[n] = *(const f16x8*)(smem + 32768 + ch * 256 + ((((ks << 2) | lq) ^ (ch & 15)) << 4));
            }
            #pragma unroll
            for (int m = 0; m < 4; ++m)
                #pragma unroll
                for (int n = 0; n < 2; ++n)
                    acc[m][n] = __builtin_amdgcn_mfma_f32_16x16x32_f16(af[m], bf[n], acc[m][n], 0, 0, 0);
        }
    }
    {   // epilogue: + fus_b, fp32 store
        float fb0 = fb[wave * 32 + lm];
        float fb1 = fb[wave * 32 + 16 + lm];
        #pragma unroll
        for (int m = 0; m < 4; ++m)
            #pragma unroll
            for (int n = 0; n < 2; ++n) {
                float fbv = n ? fb1 : fb0;
                int ch = wave * 32 + n * 16 + lm;
                #pragma unroll
                for (int r = 0; r < 4; ++r)
                    out[(size_t)(r0 + m * 16 + rbase + r) * HH + ch] = acc[m][n][r] + fbv;
            }
    }
}

// ---------------------------------------------------------------------------
extern "C" void kernel_launch(void* const* d_in, const int* in_sizes, int n_in,
                              void* d_out, int out_size, void* d_ws, size_t ws_size,
                              hipStream_t stream)
{
    const float* X      = (const float*)d_in[0];
    const float* dist   = (const float*)d_in[1];
    const float* sigmas = (const float*)d_in[2];
    const float* Ww     = (const float*)d_in[3];
    const float* Wb     = (const float*)d_in[4];
    const float* ai     = (const float*)d_in[5];
    const float* aj     = (const float*)d_in[6];
    const float* ab     = (const float*)d_in[7];
    const float* thr    = (const float*)d_in[8];
    const float* fw     = (const float*)d_in[9];
    const float* fb     = (const float*)d_in[10];
    float* out = (float*)d_out;

    // ws layout
    char* ws = (char*)d_ws;
    float*     w_ai = (float*)(ws);                    //   1 KB
    float*     w_aj = (float*)(ws + 1024);             //   1 KB
    float*     cst  = (float*)(ws + 2048);             //  32 B (pad to 4096)
    float*     srow = (float*)(ws + 4096);             // 128 KB
    float*     scol = (float*)(ws + 135168);           // 128 KB
    _Float16*  h_t  = (_Float16*)(ws + 266240);        // 8 MB
    _Float16*  Hcat = (_Float16*)(ws + 8654848);       // 8 MB
    _Float16*  g1   = (_Float16*)(ws + 17043456);      // 16 MB
    float*     g2   = (float*)(ws + 33820672);         // 32 MB -> end 67375104
    const bool geo = ws_size >= (size_t)67375104;

    k0_proj<<<1, 256, 0, stream>>>(Ww, Wb, ai, aj, ab, w_ai, w_aj, cst);
    prep_kernel<<<dim3(NN / 64, BB, SS), 256, 0, stream>>>(X, Ww, Wb, w_ai, w_aj, cst, h_t, srow, scol);
    if (geo) {
        geo_kernel<<<(SS * NN * NN / 8) / 256, 256, 0, stream>>>(dist, sigmas, thr, g1, g2);
        attn_kernel<true><<<dim3(NN / 32, BB, SS), 256, 0, stream>>>(
            dist, sigmas, thr, h_t, srow, scol, g1, g2, Hcat);
    } else {
        attn_kernel<false><<<dim3(NN / 32, BB, SS), 256, 0, stream>>>(
            dist, sigmas, thr, h_t, srow, scol, (const _Float16*)nullptr, (const float*)nullptr, Hcat);
    }
    fuse_kernel<<<BB * NN / 64, 256, 0, stream>>>(Hcat, fw, fb, out);
}